// Round 5
// baseline (542.081 us; speedup 1.0000x reference)
//
#include <hip/hip_runtime.h>
#include <cfloat>
#include <cmath>

#define NROWS 65536
#define DDIM 256
#define KDIM 4096

typedef short bf16x8 __attribute__((ext_vector_type(8)));
typedef float f32x4 __attribute__((ext_vector_type(4)));

constexpr float EPSV = 1e-5f;
constexpr float DECAYV = 0.99f;
constexpr float MOMV = 0.1f;
constexpr float DELTA = 0.4f;   // bf16 GEMM noise sigma~0.03; 0.4 >= 12 sigma
constexpr int CAP = 16;

// ---------------- workspace layout (float offsets) ----------------
constexpr size_t WS_CNT     = 0;                               // int[N] cand counts (zeroed)
constexpr size_t WS_NFLAG   = WS_CNT + NROWS;                  // int[1]+pad (zeroed)
constexpr size_t WS_HIST    = WS_NFLAG + 64;                   // int[K] (zeroed)
constexpr size_t WS_ZEND    = WS_HIST + KDIM;                  // end of zeroed region
constexpr size_t WS_START   = WS_ZEND;                         // int[K]
constexpr size_t WS_FILLPOS = WS_START + KDIM;                 // int[K]
constexpr size_t WS_PARTSUM = WS_FILLPOS + KDIM;               // [2048][256]
constexpr size_t WS_PARTSQ  = WS_PARTSUM + 2048 * DDIM;        // [2048][256]
constexpr size_t WS_MIDSUM  = WS_PARTSQ + 2048 * DDIM;         // [256][256]
constexpr size_t WS_MIDSQ   = WS_MIDSUM + 256 * DDIM;          // [256][256]
constexpr size_t WS_MEAN    = WS_MIDSQ + 256 * DDIM;           // [256]
constexpr size_t WS_RSTD    = WS_MEAN + DDIM;                  // [256]
constexpr size_t WS_NRMEAN  = WS_RSTD + DDIM;                  // [256]
constexpr size_t WS_NRVAR   = WS_NRMEAN + DDIM;                // [256]
constexpr size_t WS_BVEC    = WS_NRVAR + DDIM;                 // [4096]
constexpr size_t WS_NCSRAW  = WS_BVEC + KDIM;                  // [4096]
constexpr size_t WS_NTOT    = WS_NCSRAW + KDIM;                // [1]+pad
constexpr size_t WS_ROWINFO = WS_NTOT + 64;                    // float4[N][2]
constexpr size_t WS_IDX     = WS_ROWINFO + 8 * (size_t)NROWS;  // int[N]
constexpr size_t WS_ROWTHR  = WS_IDX + NROWS;                  // float[N]
constexpr size_t WS_FLAG    = WS_ROWTHR + NROWS;               // int[N]
constexpr size_t WS_ROWLIST = WS_FLAG + NROWS;                 // int[N]
constexpr size_t WS_CAND    = WS_ROWLIST + NROWS;              // int[N*CAP]
constexpr size_t WS_EPROW   = WS_CAND + (size_t)NROWS * CAP;   // float[K][D]
constexpr size_t WS_EIMG    = WS_EPROW + (size_t)KDIM * DDIM;  // bf16 E image 2MB
constexpr size_t WS_XIMG    = WS_EIMG + 524288;                // bf16 X image 32MB

// ---------------- output layout (float offsets) ----------------
constexpr size_t O_IDX   = 0;
constexpr size_t O_EMB   = NROWS;
constexpr size_t O_EOUT  = O_EMB + (size_t)KDIM * DDIM;
constexpr size_t O_CS    = O_EOUT + (size_t)KDIM * DDIM;
constexpr size_t O_EMAW  = O_CS + KDIM;
constexpr size_t O_RMEAN = O_EMAW + (size_t)KDIM * DDIM;
constexpr size_t O_RVAR  = O_RMEAN + DDIM;

__device__ inline unsigned bfpack(float a, float b) {   // RNE f32->bf16 pair
    unsigned ua = __float_as_uint(a), ub = __float_as_uint(b);
    ua = (ua + 0x7FFFu + ((ua >> 16) & 1u)) >> 16;
    ub = (ub + 0x7FFFu + ((ub >> 16) & 1u)) & 0xFFFF0000u;
    return (ua & 0xFFFFu) | ub;
}

#define GLOAD_LDS16(g, l) __builtin_amdgcn_global_load_lds(                       \
        (const __attribute__((address_space(1))) void*)(g),                        \
        (__attribute__((address_space(3))) void*)(l), 16, 0, 0)

// ===== K1: BN partial sums + fused x -> bf16 rotated image (2048 blocks) =====
__global__ __launch_bounds__(128) void k_bnpack(const float* __restrict__ x,
                                                float* __restrict__ ws) {
    const int t = threadIdx.x;      // d-pair 0..127
    const int b = blockIdx.x;       // 2048 blocks, 32 rows each
    char* ximg = (char*)(ws + WS_XIMG);
    float s0 = 0.f, s1 = 0.f, q0 = 0.f, q1 = 0.f;
    const int r0 = b * 32;
#pragma unroll 4
    for (int i = 0; i < 32; ++i) {
        const int r = r0 + i;
        const float2 v = *(const float2*)(x + (size_t)r * DDIM + 2 * t);
        s0 += v.x; s1 += v.y; q0 += v.x * v.x; q1 += v.y * v.y;
        const int db = (4 * t + ((r & 15) << 5)) & 511;
        *(unsigned*)(ximg + (size_t)r * 512 + db) = bfpack(v.x, v.y);
    }
    *(float2*)(ws + WS_PARTSUM + (size_t)b * DDIM + 2 * t) = make_float2(s0, s1);
    *(float2*)(ws + WS_PARTSQ  + (size_t)b * DDIM + 2 * t) = make_float2(q0, q1);
}

// ===== K1b: reduce 2048 partials -> 256 =====
__global__ __launch_bounds__(256) void k_bn_mid(float* __restrict__ ws) {
    const int d = threadIdx.x, j = blockIdx.x;
    float s = 0.f, q = 0.f;
#pragma unroll
    for (int i = 0; i < 8; ++i) {
        s += ws[WS_PARTSUM + (size_t)(j * 8 + i) * DDIM + d];
        q += ws[WS_PARTSQ  + (size_t)(j * 8 + i) * DDIM + d];
    }
    ws[WS_MIDSUM + (size_t)j * DDIM + d] = s;
    ws[WS_MIDSQ  + (size_t)j * DDIM + d] = q;
}

// ===== K2: finalize BN stats =====
__global__ __launch_bounds__(256) void k_bn_final(const float* __restrict__ rmean_in,
                                                  const float* __restrict__ rvar_in,
                                                  float* __restrict__ ws,
                                                  float* __restrict__ out) {
    const int d = threadIdx.x;
    float s = 0.f, sq = 0.f;
    for (int b = 0; b < 256; ++b) {
        s  += ws[WS_MIDSUM + (size_t)b * DDIM + d];
        sq += ws[WS_MIDSQ  + (size_t)b * DDIM + d];
    }
    const float mean = s / (float)NROWS;
    float var = sq / (float)NROWS - mean * mean;
    var = fmaxf(var, 0.f);
    const float rstd = 1.0f / sqrtf(var + EPSV);
    const float nrm  = (1.0f - MOMV) * rmean_in[d] + MOMV * mean;
    const float varu = var * ((float)NROWS / (float)(NROWS - 1));
    const float nrv  = (1.0f - MOMV) * rvar_in[d] + MOMV * varu;
    ws[WS_MEAN + d] = mean;
    ws[WS_RSTD + d] = rstd;
    ws[WS_NRMEAN + d] = nrm;
    ws[WS_NRVAR + d] = nrv;
    out[O_RMEAN + d] = nrm;
    out[O_RVAR + d] = nrv;
}

// ===== K3: e' fp32 rows + bf16 rotated image + b_k =====
__global__ __launch_bounds__(128) void k_eprime(const float* __restrict__ emb,
                                                float* __restrict__ ws) {
    __shared__ float red[128];
    const int k = blockIdx.x, t = threadIdx.x;
    const int d0 = 2 * t, d1 = 2 * t + 1;
    const float em0 = emb[(size_t)k * DDIM + d0], em1 = emb[(size_t)k * DDIM + d1];
    const float rs0 = ws[WS_RSTD + d0], rs1 = ws[WS_RSTD + d1];
    const float mn0 = ws[WS_MEAN + d0], mn1 = ws[WS_MEAN + d1];
    const float e0 = em0 * rs0, e1 = em1 * rs1;
    ws[WS_EPROW + (size_t)k * DDIM + d0] = e0;
    ws[WS_EPROW + (size_t)k * DDIM + d1] = e1;
    char* img = (char*)(ws + WS_EIMG);
    const int db = (4 * t + ((k & 15) << 5)) & 511;
    *(unsigned*)(img + (size_t)k * 512 + db) = bfpack(e0, e1);
    red[t] = em0 * em0 + 2.f * mn0 * e0 + em1 * em1 + 2.f * mn1 * e1;
    __syncthreads();
    for (int s = 64; s > 0; s >>= 1) { if (t < s) red[t] += red[t + s]; __syncthreads(); }
    if (t == 0) ws[WS_BVEC + k] = red[0];
}

// ===== K4: single-pass MFMA GEMM, 64 rows/wave, unpacked top-2 =====
// 512 blocks = 256 row-tiles x 2 col-halves; 4 waves x 64 rows each.
// A frags in regs (128 VGPR); LDS: 2 x 16KB E-chunk dbuf -> B LDS traffic halved.
__global__ __launch_bounds__(256, 2) void k_gemm_min(float* __restrict__ ws) {
    extern __shared__ char smem[];      // 2 x 16384
    const int t = threadIdx.x, lane = t & 63, w = t >> 6;
    const int l4 = lane & 15, kg = lane >> 4;
    const int tile = blockIdx.x >> 1;
    const int chh  = blockIdx.x & 1;
    const int rowbase = tile * 256 + w * 64;
    const char* ximg = (const char*)(ws + WS_XIMG);
    const char* eimg = (const char*)(ws + WS_EIMG) + (size_t)chh * 1048576;  // 2048 cols
    const float* bvec = ws + WS_BVEC;

    // A fragments: rows rowbase + m*16 + l4, all 8 k-steps (rotated image)
    bf16x8 a[4][8];
#pragma unroll
    for (int m = 0; m < 4; ++m) {
        const char* rp = ximg + (size_t)(rowbase + m * 16 + l4) * 512;
#pragma unroll
        for (int ts = 0; ts < 8; ++ts) {
            const int byte = ((kg * 16 + ts * 64) + (l4 << 5)) & 511;
            a[m][ts] = *(const bf16x8*)(rp + byte);
        }
    }

    float b1v[4][4], b2v[4][4];
    int b1i[4][4];
#pragma unroll
    for (int m = 0; m < 4; ++m)
#pragma unroll
        for (int r = 0; r < 4; ++r) { b1v[m][r] = FLT_MAX; b2v[m][r] = FLT_MAX; b1i[m][r] = 0; }

    // prologue: stage chunk 0 (16KB)
#pragma unroll
    for (int rr = 0; rr < 4; ++rr) {
        const int off = rr * 4096 + w * 1024;
        GLOAD_LDS16(eimg + off + lane * 16, smem + off);
    }
    __syncthreads();

    for (int ch = 0; ch < 64; ++ch) {
        const char* cur = smem + (ch & 1) * 16384;
        if (ch + 1 < 64) {
            const char* src = eimg + (size_t)(ch + 1) * 16384;
            char* nb = smem + ((ch + 1) & 1) * 16384;
#pragma unroll
            for (int rr = 0; rr < 4; ++rr) {
                const int off = rr * 4096 + w * 1024;
                GLOAD_LDS16(src + off + lane * 16, nb + off);
            }
        }

        f32x4 acc[4][2];
#pragma unroll
        for (int m = 0; m < 4; ++m)
#pragma unroll
            for (int n = 0; n < 2; ++n) acc[m][n] = 0.f;

#pragma unroll
        for (int ts = 0; ts < 8; ++ts) {
            const int rot = ((kg * 16 + ts * 64) + (l4 << 5)) & 511;
            bf16x8 bfr[2];
#pragma unroll
            for (int n = 0; n < 2; ++n)
                bfr[n] = *(const bf16x8*)(cur + (n * 16 + l4) * 512 + rot);
#pragma unroll
            for (int m = 0; m < 4; ++m)
#pragma unroll
                for (int n = 0; n < 2; ++n)
                    acc[m][n] = __builtin_amdgcn_mfma_f32_16x16x32_bf16(a[m][ts], bfr[n], acc[m][n], 0, 0, 0);
        }

#pragma unroll
        for (int n = 0; n < 2; ++n) {
            const int col = chh * 2048 + ch * 32 + n * 16 + l4;
            const float bc = bvec[col];
#pragma unroll
            for (int m = 0; m < 4; ++m)
#pragma unroll
                for (int r = 0; r < 4; ++r) {
                    const float s = fmaf(-2.f, acc[m][n][r], bc);
                    const bool lt = s < b1v[m][r];
                    b2v[m][r] = lt ? b1v[m][r] : fminf(b2v[m][r], s);
                    b1i[m][r] = lt ? col : b1i[m][r];
                    b1v[m][r] = lt ? s : b1v[m][r];
                }
        }
        __syncthreads();   // drains prefetch + protects cur reuse
    }

    // merge top-2 across the 16 l4-lanes holding each row; write partial
    float4* rowinfo = (float4*)(ws + WS_ROWINFO);
#pragma unroll
    for (int m = 0; m < 4; ++m)
#pragma unroll
        for (int r = 0; r < 4; ++r) {
            float v1 = b1v[m][r], v2 = b2v[m][r];
            int i1 = b1i[m][r];
#pragma unroll
            for (int st = 1; st < 16; st <<= 1) {
                const float o1 = __shfl_xor(v1, st);
                const int   oi = __shfl_xor(i1, st);
                const float o2 = __shfl_xor(v2, st);
                const bool lt = o1 < v1;
                v2 = lt ? fminf(v1, o2) : fminf(v2, o1);
                i1 = lt ? oi : i1;
                v1 = fminf(v1, o1);
            }
            if (l4 == 0) {
                const int row = rowbase + m * 16 + kg * 4 + r;
                rowinfo[(size_t)row * 2 + chh] =
                    make_float4(v1, __int_as_float(i1), v2, 0.f);
            }
        }
}

// ===== K5: merge col-half partials, flag close rows, decide clear rows =====
__global__ __launch_bounds__(256) void k_flag(float* __restrict__ ws,
                                              float* __restrict__ out) {
    const int r = blockIdx.x * 256 + threadIdx.x;
    const float4* rowinfo = (const float4*)(ws + WS_ROWINFO);
    const float4 p0 = rowinfo[(size_t)r * 2];
    const float4 p1 = rowinfo[(size_t)r * 2 + 1];
    const bool lt = p1.x < p0.x;
    const float v1 = lt ? p1.x : p0.x;
    const int   i1 = __float_as_int(lt ? p1.y : p0.y);
    const float v2 = lt ? fminf(p0.x, p1.z) : fminf(p1.x, p0.z);
    ws[WS_ROWTHR + r] = v1 + DELTA;
    if (v2 - v1 <= DELTA) {
        const int pos = atomicAdd((int*)(ws + WS_NFLAG), 1);
        ((int*)(ws + WS_FLAG))[pos] = r;
    } else {
        out[O_IDX + r] = (float)i1;
        ((int*)(ws + WS_IDX))[r] = i1;
    }
}

// ===== K6: candidate-append mini-GEMM over flagged rows, col-sliced x8 =====
__global__ __launch_bounds__(256) void k_cand(float* __restrict__ ws) {
    extern __shared__ char smem[];      // 2 x 16384
    const int t = threadIdx.x, lane = t & 63, w = t >> 6;
    const int l4 = lane & 15, kg = lane >> 4;
    const char* ximg = (const char*)(ws + WS_XIMG);
    const char* eimg0 = (const char*)(ws + WS_EIMG);
    const float* bvec = ws + WS_BVEC;
    const int* flag = (const int*)(ws + WS_FLAG);
    int* cnt = (int*)(ws + WS_CNT);
    int* cand = (int*)(ws + WS_CAND);
    const int nflag = *(const int*)(ws + WS_NFLAG);
    if (nflag == 0) return;
    const int ntiles = (nflag + 127) >> 7;
    const int nitems = ntiles * 8;

    for (int item = blockIdx.x; item < nitems; item += gridDim.x) {
        const int tile = item >> 3, slice = item & 7;
        const int base = tile * 128 + w * 32;
        const char* eimg = eimg0 + (size_t)slice * 262144;   // 512 cols per slice
        bf16x8 a[2][8];
        int frow[2][4];
        float thr[2][4];
#pragma unroll
        for (int m = 0; m < 2; ++m) {
            const int ia = base + m * 16 + l4;
            const int rowa = flag[ia < nflag ? ia : (nflag - 1)];
            const char* rp = ximg + (size_t)rowa * 512;
#pragma unroll
            for (int ts = 0; ts < 8; ++ts) {
                const int byte = ((kg * 16 + ts * 64) + ((rowa & 15) << 5)) & 511;
                a[m][ts] = *(const bf16x8*)(rp + byte);
            }
#pragma unroll
            for (int r = 0; r < 4; ++r) {
                const int ie = base + m * 16 + kg * 4 + r;
                const bool val = ie < nflag;
                const int rowe = flag[val ? ie : (nflag - 1)];
                frow[m][r] = rowe;
                thr[m][r] = val ? ws[WS_ROWTHR + rowe] : -FLT_MAX;
            }
        }
#pragma unroll
        for (int rr = 0; rr < 4; ++rr) {
            const int off = rr * 4096 + w * 1024;
            GLOAD_LDS16(eimg + off + lane * 16, smem + off);
        }
        __syncthreads();

        for (int ch = 0; ch < 16; ++ch) {
            const char* cur = smem + (ch & 1) * 16384;
            if (ch + 1 < 16) {
                const char* src = eimg + (size_t)(ch + 1) * 16384;
                char* nb = smem + ((ch + 1) & 1) * 16384;
#pragma unroll
                for (int rr = 0; rr < 4; ++rr) {
                    const int off = rr * 4096 + w * 1024;
                    GLOAD_LDS16(src + off + lane * 16, nb + off);
                }
            }
            f32x4 acc[2][2];
#pragma unroll
            for (int m = 0; m < 2; ++m)
#pragma unroll
                for (int n = 0; n < 2; ++n) acc[m][n] = 0.f;
#pragma unroll
            for (int ts = 0; ts < 8; ++ts) {
                const int rot = ((kg * 16 + ts * 64) + (l4 << 5)) & 511;
                bf16x8 bfr[2];
#pragma unroll
                for (int n = 0; n < 2; ++n)
                    bfr[n] = *(const bf16x8*)(cur + (n * 16 + l4) * 512 + rot);
#pragma unroll
                for (int m = 0; m < 2; ++m)
#pragma unroll
                    for (int n = 0; n < 2; ++n)
                        acc[m][n] = __builtin_amdgcn_mfma_f32_16x16x32_bf16(a[m][ts], bfr[n], acc[m][n], 0, 0, 0);
            }
#pragma unroll
            for (int n = 0; n < 2; ++n) {
                const int col = slice * 512 + ch * 32 + n * 16 + l4;
                const float bc = bvec[col];
#pragma unroll
                for (int m = 0; m < 2; ++m)
#pragma unroll
                    for (int r = 0; r < 4; ++r) {
                        const float s = fmaf(-2.f, acc[m][n][r], bc);
                        if (s <= thr[m][r]) {
                            const int rr2 = frow[m][r];
                            const int pos = atomicAdd(&cnt[rr2], 1);
                            if (pos < CAP) cand[(size_t)rr2 * CAP + pos] = col;
                        }
                    }
            }
            __syncthreads();
        }
    }
}

// ===== K7: exact fp32 resolve for flagged rows =====
__global__ __launch_bounds__(256) void k_resolve_f(const float* __restrict__ x,
                                                   float* __restrict__ ws,
                                                   float* __restrict__ out) {
    const int t = threadIdx.x, lane = t & 63;
    const int gw = (blockIdx.x * 256 + t) >> 6;     // 1024 waves
    const int nflag = *(const int*)(ws + WS_NFLAG);
    const int* flag = (const int*)(ws + WS_FLAG);
    const int* cnt = (const int*)(ws + WS_CNT);
    const int* cand = (const int*)(ws + WS_CAND);
    const float* eprow = ws + WS_EPROW;
    const float* bvec = ws + WS_BVEC;
    int* idx_int = (int*)(ws + WS_IDX);
    for (int i = gw; i < nflag; i += 1024) {
        const int row = flag[i];
        const float4 xr = ((const float4*)(x + (size_t)row * DDIM))[lane];
        const int n = cnt[row];
        float bestv = FLT_MAX;
        int bestk = KDIM;
        if (n >= 1 && n <= CAP) {
            for (int c = 0; c < n; ++c) {
                const int k = cand[(size_t)row * CAP + c];
                const float4 er = ((const float4*)(eprow + (size_t)k * DDIM))[lane];
                float p = xr.x * er.x + xr.y * er.y + xr.z * er.z + xr.w * er.w;
                p += __shfl_xor(p, 32); p += __shfl_xor(p, 16); p += __shfl_xor(p, 8);
                p += __shfl_xor(p, 4);  p += __shfl_xor(p, 2);  p += __shfl_xor(p, 1);
                const float s = fmaf(-2.f, p, bvec[k]);
                if (s < bestv || (s == bestv && k < bestk)) { bestv = s; bestk = k; }
            }
        } else {   // overflow / safety fallback: exact full scan
            for (int k = 0; k < KDIM; ++k) {
                const float4 er = ((const float4*)(eprow + (size_t)k * DDIM))[lane];
                float p = xr.x * er.x + xr.y * er.y + xr.z * er.z + xr.w * er.w;
                p += __shfl_xor(p, 32); p += __shfl_xor(p, 16); p += __shfl_xor(p, 8);
                p += __shfl_xor(p, 4);  p += __shfl_xor(p, 2);  p += __shfl_xor(p, 1);
                const float s = fmaf(-2.f, p, bvec[k]);
                if (s < bestv || (s == bestv && k < bestk)) { bestv = s; bestk = k; }
            }
        }
        if (lane == 0) { out[O_IDX + row] = (float)bestk; idx_int[row] = bestk; }
    }
}

// ===== K8a: histogram of cluster assignments (int atomics) =====
__global__ __launch_bounds__(256) void k_hist(float* __restrict__ ws) {
    const int r = blockIdx.x * 256 + threadIdx.x;
    const int k = ((const int*)(ws + WS_IDX))[r];
    atomicAdd((int*)(ws + WS_HIST) + k, 1);
}

// ===== K8b: exclusive prefix sum over 4096 counts (single block) =====
__global__ __launch_bounds__(256) void k_scan(float* __restrict__ ws) {
    __shared__ int lsum[256];
    const int t = threadIdx.x;
    const int* hist = (const int*)(ws + WS_HIST);
    int* start = (int*)(ws + WS_START);
    int* fillpos = (int*)(ws + WS_FILLPOS);
    int s = 0;
#pragma unroll
    for (int i = 0; i < 16; ++i) s += hist[t * 16 + i];
    lsum[t] = s;
    __syncthreads();
    int v = s;
    for (int off = 1; off < 256; off <<= 1) {
        const int add = (t >= off) ? lsum[t - off] : 0;
        __syncthreads();
        v += add;
        lsum[t] = v;
        __syncthreads();
    }
    int running = v - s;          // exclusive prefix of this 16-group
#pragma unroll
    for (int i = 0; i < 16; ++i) {
        const int h = hist[t * 16 + i];
        start[t * 16 + i] = running;
        fillpos[t * 16 + i] = running;
        running += h;
    }
}

// ===== K8c: fill per-cluster row lists =====
__global__ __launch_bounds__(256) void k_fill(float* __restrict__ ws) {
    const int r = blockIdx.x * 256 + threadIdx.x;
    const int k = ((const int*)(ws + WS_IDX))[r];
    const int pos = atomicAdd((int*)(ws + WS_FILLPOS) + k, 1);
    ((int*)(ws + WS_ROWLIST))[pos] = r;
}

// ===== K9a: EMA cluster size + n_total =====
__global__ __launch_bounds__(256) void k_ema_cs(const float* __restrict__ cs_in,
                                                float* __restrict__ ws) {
    __shared__ float red[256];
    const int t = threadIdx.x;
    const int* hist = (const int*)(ws + WS_HIST);
    float part = 0.f;
    for (int k = t; k < KDIM; k += 256) {
        const float ncs = cs_in[k] * DECAYV + (1.0f - DECAYV) * (float)hist[k];
        ws[WS_NCSRAW + k] = ncs;
        part += ncs;
    }
    red[t] = part;
    __syncthreads();
    for (int s = 128; s > 0; s >>= 1) { if (t < s) red[t] += red[t + s]; __syncthreads(); }
    if (t == 0) ws[WS_NTOT] = red[0];
}

// ===== K9b: fused per-cluster gather-sum + finalize [K,D] outputs =====
__global__ __launch_bounds__(256) void k_final(const float* __restrict__ x,
                                               const float* __restrict__ ema_w,
                                               const float* __restrict__ ws,
                                               float* __restrict__ out) {
    const int k = blockIdx.x;   // 4096 blocks, one per cluster
    const int d = threadIdx.x;
    const int st = ((const int*)(ws + WS_START))[k];
    const int n  = ((const int*)(ws + WS_HIST))[k];
    const int* rowlist = (const int*)(ws + WS_ROWLIST);
    float s0 = 0.f, s1 = 0.f;
    int i = 0;
    for (; i + 1 < n; i += 2) {
        s0 += x[(size_t)rowlist[st + i] * DDIM + d];
        s1 += x[(size_t)rowlist[st + i + 1] * DDIM + d];
    }
    if (i < n) s0 += x[(size_t)rowlist[st + i] * DDIM + d];
    const float dwsum = s0 + s1;
    const float ntot = ws[WS_NTOT];
    const float ncs  = (ws[WS_NCSRAW + k] + 1e-5f) / (ntot + (float)KDIM * 1e-5f) * ntot;
    const float mn   = ws[WS_MEAN + d];
    const float rs   = ws[WS_RSTD + d];
    const size_t e   = (size_t)k * DDIM + d;
    const float dw   = (dwsum - (float)n * mn) * rs;
    const float nw   = ema_w[e] * DECAYV + (1.0f - DECAYV) * dw;
    const float nemb = nw / ncs;
    const float eo   = nemb * sqrtf(ws[WS_NRVAR + d] + EPSV) + ws[WS_NRMEAN + d];
    out[O_EMB + e]  = nemb;
    out[O_EOUT + e] = eo;
    out[O_EMAW + e] = nw;
    if (d == 0) out[O_CS + k] = ncs;
}

// ===== launcher =====
extern "C" void kernel_launch(void* const* d_in, const int* in_sizes, int n_in,
                              void* d_out, int out_size, void* d_ws, size_t ws_size,
                              hipStream_t stream) {
    const float* x     = (const float*)d_in[0];
    const float* emb   = (const float*)d_in[1];
    const float* cs    = (const float*)d_in[2];
    const float* ema_w = (const float*)d_in[3];
    const float* rmean = (const float*)d_in[4];
    const float* rvar  = (const float*)d_in[5];
    float* out = (float*)d_out;
    float* ws  = (float*)d_ws;

    // zero cnt + nflag + hist (contiguous at ws base, ~280 KB)
    hipMemsetAsync(ws, 0, WS_ZEND * sizeof(float), stream);

    k_bnpack<<<2048, 128, 0, stream>>>(x, ws);
    k_bn_mid<<<256, 256, 0, stream>>>(ws);
    k_bn_final<<<1, 256, 0, stream>>>(rmean, rvar, ws, out);
    k_eprime<<<KDIM, 128, 0, stream>>>(emb, ws);

    constexpr int LDSB = 32768;
    k_gemm_min<<<512, 256, LDSB, stream>>>(ws);
    k_flag<<<NROWS / 256, 256, 0, stream>>>(ws, out);
    k_cand<<<512, 256, LDSB, stream>>>(ws);
    k_resolve_f<<<256, 256, 0, stream>>>(x, ws, out);

    k_hist<<<NROWS / 256, 256, 0, stream>>>(ws);
    k_scan<<<1, 256, 0, stream>>>(ws);
    k_fill<<<NROWS / 256, 256, 0, stream>>>(ws);
    k_ema_cs<<<1, 256, 0, stream>>>(cs, ws);
    k_final<<<KDIM, 256, 0, stream>>>(x, ema_w, ws, out);
}

// Round 6
// 321.060 us; speedup vs baseline: 1.6884x; 1.6884x over previous
//
#include <hip/hip_runtime.h>
#include <cfloat>
#include <cmath>

#define NROWS 65536
#define DDIM 256
#define KDIM 4096

typedef short bf16x8 __attribute__((ext_vector_type(8)));
typedef float f32x4 __attribute__((ext_vector_type(4)));

constexpr float EPSV = 1e-5f;
constexpr float DECAYV = 0.99f;
constexpr float MOMV = 0.1f;
constexpr float DELTA = 0.4f;   // bf16 GEMM noise sigma~0.03; 0.4 >= 12 sigma
constexpr int CAP = 16;
constexpr int SEG = 128;        // rows per gather segment

// ---------------- workspace layout (float offsets) ----------------
constexpr size_t WS_CNT     = 0;                               // int[N] cand counts (zeroed)
constexpr size_t WS_NFLAG   = WS_CNT + NROWS;                  // int[1]+pad (zeroed)
constexpr size_t WS_HIST    = WS_NFLAG + 64;                   // int[K] (zeroed)
constexpr size_t WS_ZEND    = WS_HIST + KDIM;                  // end of zeroed region
constexpr size_t WS_START   = WS_ZEND;                         // int[K]
constexpr size_t WS_FILLPOS = WS_START + KDIM;                 // int[K]
constexpr size_t WS_SEGSTART= WS_FILLPOS + KDIM;               // int[K+64]
constexpr size_t WS_NSEG    = WS_SEGSTART + KDIM + 64;         // int[1]+pad
constexpr size_t WS_SEGLIST = WS_NSEG + 64;                    // int[4608+pad]
constexpr size_t WS_PARTSUM = WS_SEGLIST + 4672;               // [2048][256]
constexpr size_t WS_PARTSQ  = WS_PARTSUM + 2048 * DDIM;        // [2048][256]
constexpr size_t WS_MIDSUM  = WS_PARTSQ + 2048 * DDIM;         // [256][256]
constexpr size_t WS_MIDSQ   = WS_MIDSUM + 256 * DDIM;          // [256][256]
constexpr size_t WS_MEAN    = WS_MIDSQ + 256 * DDIM;           // [256]
constexpr size_t WS_RSTD    = WS_MEAN + DDIM;                  // [256]
constexpr size_t WS_NRMEAN  = WS_RSTD + DDIM;                  // [256]
constexpr size_t WS_NRVAR   = WS_NRMEAN + DDIM;                // [256]
constexpr size_t WS_BVEC    = WS_NRVAR + DDIM;                 // [4096]
constexpr size_t WS_NCSRAW  = WS_BVEC + KDIM;                  // [4096]
constexpr size_t WS_NTOT    = WS_NCSRAW + KDIM;                // [1]+pad
constexpr size_t WS_ROWINFO = WS_NTOT + 64;                    // float4[N][4]
constexpr size_t WS_IDX     = WS_ROWINFO + 16 * (size_t)NROWS; // int[N]
constexpr size_t WS_ROWTHR  = WS_IDX + NROWS;                  // float[N]
constexpr size_t WS_FLAG    = WS_ROWTHR + NROWS;               // int[N]
constexpr size_t WS_ROWLIST = WS_FLAG + NROWS;                 // int[N]
constexpr size_t WS_CAND    = WS_ROWLIST + NROWS;              // int[N*CAP]
constexpr size_t WS_DWPART  = WS_CAND;                         // ALIAS: float[4608][256] over CAND+EPROW (dead by then)
constexpr size_t WS_EPROW   = WS_CAND + (size_t)NROWS * CAP;   // float[K][D]
constexpr size_t WS_EIMG    = WS_EPROW + (size_t)KDIM * DDIM;  // bf16 E image 2MB
constexpr size_t WS_XIMG    = WS_EIMG + 524288;                // bf16 X image 32MB

// ---------------- output layout (float offsets) ----------------
constexpr size_t O_IDX   = 0;
constexpr size_t O_EMB   = NROWS;
constexpr size_t O_EOUT  = O_EMB + (size_t)KDIM * DDIM;
constexpr size_t O_CS    = O_EOUT + (size_t)KDIM * DDIM;
constexpr size_t O_EMAW  = O_CS + KDIM;
constexpr size_t O_RMEAN = O_EMAW + (size_t)KDIM * DDIM;
constexpr size_t O_RVAR  = O_RMEAN + DDIM;

__device__ inline unsigned bfpack(float a, float b) {   // RNE f32->bf16 pair
    unsigned ua = __float_as_uint(a), ub = __float_as_uint(b);
    ua = (ua + 0x7FFFu + ((ua >> 16) & 1u)) >> 16;
    ub = (ub + 0x7FFFu + ((ub >> 16) & 1u)) & 0xFFFF0000u;
    return (ua & 0xFFFFu) | ub;
}

#define GLOAD_LDS16(g, l) __builtin_amdgcn_global_load_lds(                       \
        (const __attribute__((address_space(1))) void*)(g),                        \
        (__attribute__((address_space(3))) void*)(l), 16, 0, 0)

// ===== K1: BN partial sums + fused x -> bf16 rotated image (2048 blocks) =====
__global__ __launch_bounds__(128) void k_bnpack(const float* __restrict__ x,
                                                float* __restrict__ ws) {
    const int t = threadIdx.x;      // d-pair 0..127
    const int b = blockIdx.x;       // 2048 blocks, 32 rows each
    char* ximg = (char*)(ws + WS_XIMG);
    float s0 = 0.f, s1 = 0.f, q0 = 0.f, q1 = 0.f;
    const int r0 = b * 32;
#pragma unroll 4
    for (int i = 0; i < 32; ++i) {
        const int r = r0 + i;
        const float2 v = *(const float2*)(x + (size_t)r * DDIM + 2 * t);
        s0 += v.x; s1 += v.y; q0 += v.x * v.x; q1 += v.y * v.y;
        const int db = (4 * t + ((r & 15) << 5)) & 511;
        *(unsigned*)(ximg + (size_t)r * 512 + db) = bfpack(v.x, v.y);
    }
    *(float2*)(ws + WS_PARTSUM + (size_t)b * DDIM + 2 * t) = make_float2(s0, s1);
    *(float2*)(ws + WS_PARTSQ  + (size_t)b * DDIM + 2 * t) = make_float2(q0, q1);
}

// ===== K1b: reduce 2048 partials -> 256 =====
__global__ __launch_bounds__(256) void k_bn_mid(float* __restrict__ ws) {
    const int d = threadIdx.x, j = blockIdx.x;
    float s = 0.f, q = 0.f;
#pragma unroll
    for (int i = 0; i < 8; ++i) {
        s += ws[WS_PARTSUM + (size_t)(j * 8 + i) * DDIM + d];
        q += ws[WS_PARTSQ  + (size_t)(j * 8 + i) * DDIM + d];
    }
    ws[WS_MIDSUM + (size_t)j * DDIM + d] = s;
    ws[WS_MIDSQ  + (size_t)j * DDIM + d] = q;
}

// ===== K2: finalize BN stats =====
__global__ __launch_bounds__(256) void k_bn_final(const float* __restrict__ rmean_in,
                                                  const float* __restrict__ rvar_in,
                                                  float* __restrict__ ws,
                                                  float* __restrict__ out) {
    const int d = threadIdx.x;
    float s = 0.f, sq = 0.f;
    for (int b = 0; b < 256; ++b) {
        s  += ws[WS_MIDSUM + (size_t)b * DDIM + d];
        sq += ws[WS_MIDSQ  + (size_t)b * DDIM + d];
    }
    const float mean = s / (float)NROWS;
    float var = sq / (float)NROWS - mean * mean;
    var = fmaxf(var, 0.f);
    const float rstd = 1.0f / sqrtf(var + EPSV);
    const float nrm  = (1.0f - MOMV) * rmean_in[d] + MOMV * mean;
    const float varu = var * ((float)NROWS / (float)(NROWS - 1));
    const float nrv  = (1.0f - MOMV) * rvar_in[d] + MOMV * varu;
    ws[WS_MEAN + d] = mean;
    ws[WS_RSTD + d] = rstd;
    ws[WS_NRMEAN + d] = nrm;
    ws[WS_NRVAR + d] = nrv;
    out[O_RMEAN + d] = nrm;
    out[O_RVAR + d] = nrv;
}

// ===== K3: e' fp32 rows + bf16 rotated image + b_k =====
__global__ __launch_bounds__(128) void k_eprime(const float* __restrict__ emb,
                                                float* __restrict__ ws) {
    __shared__ float red[128];
    const int k = blockIdx.x, t = threadIdx.x;
    const int d0 = 2 * t, d1 = 2 * t + 1;
    const float em0 = emb[(size_t)k * DDIM + d0], em1 = emb[(size_t)k * DDIM + d1];
    const float rs0 = ws[WS_RSTD + d0], rs1 = ws[WS_RSTD + d1];
    const float mn0 = ws[WS_MEAN + d0], mn1 = ws[WS_MEAN + d1];
    const float e0 = em0 * rs0, e1 = em1 * rs1;
    ws[WS_EPROW + (size_t)k * DDIM + d0] = e0;
    ws[WS_EPROW + (size_t)k * DDIM + d1] = e1;
    char* img = (char*)(ws + WS_EIMG);
    const int db = (4 * t + ((k & 15) << 5)) & 511;
    *(unsigned*)(img + (size_t)k * 512 + db) = bfpack(e0, e1);
    red[t] = em0 * em0 + 2.f * mn0 * e0 + em1 * em1 + 2.f * mn1 * e1;
    __syncthreads();
    for (int s = 64; s > 0; s >>= 1) { if (t < s) red[t] += red[t + s]; __syncthreads(); }
    if (t == 0) ws[WS_BVEC + k] = red[0];
}

// ===== K4: single-pass MFMA GEMM, 32 rows/wave, col-quartered grid =====
// 2048 blocks = 512 row-tiles x 4 col-quarters; 4 waves x 32 rows each.
// LDS: 2 x 16KB E-chunk dbuf; grid gives 8 blocks/CU available, LB(256,3)
// targets 3 waves/SIMD co-resident for latency hiding.
__global__ __launch_bounds__(256, 3) void k_gemm_min(float* __restrict__ ws) {
    extern __shared__ char smem[];      // 2 x 16384
    const int t = threadIdx.x, lane = t & 63, w = t >> 6;
    const int l4 = lane & 15, kg = lane >> 4;
    const int tile = blockIdx.x >> 2;
    const int cq   = blockIdx.x & 3;
    const int rowbase = tile * 128 + w * 32;
    const char* ximg = (const char*)(ws + WS_XIMG);
    const char* eimg = (const char*)(ws + WS_EIMG) + (size_t)cq * 524288;  // 1024 cols
    const float* bvec = ws + WS_BVEC;

    // A fragments: rows rowbase + m*16 + l4, all 8 k-steps (rotated image)
    bf16x8 a[2][8];
#pragma unroll
    for (int m = 0; m < 2; ++m) {
        const char* rp = ximg + (size_t)(rowbase + m * 16 + l4) * 512;
#pragma unroll
        for (int ts = 0; ts < 8; ++ts) {
            const int byte = ((kg * 16 + ts * 64) + (l4 << 5)) & 511;
            a[m][ts] = *(const bf16x8*)(rp + byte);
        }
    }

    float b1v[2][4], b2v[2][4];
    int b1i[2][4];
#pragma unroll
    for (int m = 0; m < 2; ++m)
#pragma unroll
        for (int r = 0; r < 4; ++r) { b1v[m][r] = FLT_MAX; b2v[m][r] = FLT_MAX; b1i[m][r] = 0; }

    // prologue: stage chunk 0 (16KB)
#pragma unroll
    for (int rr = 0; rr < 4; ++rr) {
        const int off = rr * 4096 + w * 1024;
        GLOAD_LDS16(eimg + off + lane * 16, smem + off);
    }
    __syncthreads();

    for (int ch = 0; ch < 32; ++ch) {
        const char* cur = smem + (ch & 1) * 16384;
        if (ch + 1 < 32) {
            const char* src = eimg + (size_t)(ch + 1) * 16384;
            char* nb = smem + ((ch + 1) & 1) * 16384;
#pragma unroll
            for (int rr = 0; rr < 4; ++rr) {
                const int off = rr * 4096 + w * 1024;
                GLOAD_LDS16(src + off + lane * 16, nb + off);
            }
        }

        f32x4 acc[2][2];
#pragma unroll
        for (int m = 0; m < 2; ++m)
#pragma unroll
            for (int n = 0; n < 2; ++n) acc[m][n] = 0.f;

#pragma unroll
        for (int ts = 0; ts < 8; ++ts) {
            const int rot = ((kg * 16 + ts * 64) + (l4 << 5)) & 511;
            bf16x8 bfr[2];
#pragma unroll
            for (int n = 0; n < 2; ++n)
                bfr[n] = *(const bf16x8*)(cur + (n * 16 + l4) * 512 + rot);
#pragma unroll
            for (int m = 0; m < 2; ++m)
#pragma unroll
                for (int n = 0; n < 2; ++n)
                    acc[m][n] = __builtin_amdgcn_mfma_f32_16x16x32_bf16(a[m][ts], bfr[n], acc[m][n], 0, 0, 0);
        }

#pragma unroll
        for (int n = 0; n < 2; ++n) {
            const int col = cq * 1024 + ch * 32 + n * 16 + l4;
            const float bc = bvec[col];
#pragma unroll
            for (int m = 0; m < 2; ++m)
#pragma unroll
                for (int r = 0; r < 4; ++r) {
                    const float s = fmaf(-2.f, acc[m][n][r], bc);
                    const bool lt = s < b1v[m][r];
                    b2v[m][r] = lt ? b1v[m][r] : fminf(b2v[m][r], s);
                    b1i[m][r] = lt ? col : b1i[m][r];
                    b1v[m][r] = lt ? s : b1v[m][r];
                }
        }
        __syncthreads();   // drains prefetch + protects cur reuse
    }

    // merge top-2 across the 16 l4-lanes holding each row; write partial
    float4* rowinfo = (float4*)(ws + WS_ROWINFO);
#pragma unroll
    for (int m = 0; m < 2; ++m)
#pragma unroll
        for (int r = 0; r < 4; ++r) {
            float v1 = b1v[m][r], v2 = b2v[m][r];
            int i1 = b1i[m][r];
#pragma unroll
            for (int st = 1; st < 16; st <<= 1) {
                const float o1 = __shfl_xor(v1, st);
                const int   oi = __shfl_xor(i1, st);
                const float o2 = __shfl_xor(v2, st);
                const bool lt = o1 < v1;
                v2 = lt ? fminf(v1, o2) : fminf(v2, o1);
                i1 = lt ? oi : i1;
                v1 = fminf(v1, o1);
            }
            if (l4 == 0) {
                const int row = rowbase + m * 16 + kg * 4 + r;
                rowinfo[(size_t)row * 4 + cq] =
                    make_float4(v1, __int_as_float(i1), v2, 0.f);
            }
        }
}

// ===== K5: merge 4 col-quarter partials, flag close rows =====
__global__ __launch_bounds__(256) void k_flag(float* __restrict__ ws,
                                              float* __restrict__ out) {
    const int r = blockIdx.x * 256 + threadIdx.x;
    const float4* rowinfo = (const float4*)(ws + WS_ROWINFO);
    float v1 = FLT_MAX, v2 = FLT_MAX;
    int i1 = 0;
#pragma unroll
    for (int c = 0; c < 4; ++c) {
        const float4 p = rowinfo[(size_t)r * 4 + c];
        const float a = p.x, b = p.z;
        if (a < v1) { v2 = fminf(fminf(v1, b), v2); v1 = a; i1 = __float_as_int(p.y); }
        else        { v2 = fminf(v2, a); }
    }
    ws[WS_ROWTHR + r] = v1 + DELTA;
    if (v2 - v1 <= DELTA) {
        const int pos = atomicAdd((int*)(ws + WS_NFLAG), 1);
        ((int*)(ws + WS_FLAG))[pos] = r;
    } else {
        out[O_IDX + r] = (float)i1;
        ((int*)(ws + WS_IDX))[r] = i1;
    }
}

// ===== K6: candidate-append mini-GEMM over flagged rows, col-sliced x8 =====
__global__ __launch_bounds__(256) void k_cand(float* __restrict__ ws) {
    extern __shared__ char smem[];      // 2 x 16384
    const int t = threadIdx.x, lane = t & 63, w = t >> 6;
    const int l4 = lane & 15, kg = lane >> 4;
    const char* ximg = (const char*)(ws + WS_XIMG);
    const char* eimg0 = (const char*)(ws + WS_EIMG);
    const float* bvec = ws + WS_BVEC;
    const int* flag = (const int*)(ws + WS_FLAG);
    int* cnt = (int*)(ws + WS_CNT);
    int* cand = (int*)(ws + WS_CAND);
    const int nflag = *(const int*)(ws + WS_NFLAG);
    if (nflag == 0) return;
    const int ntiles = (nflag + 127) >> 7;
    const int nitems = ntiles * 8;

    for (int item = blockIdx.x; item < nitems; item += gridDim.x) {
        const int tile = item >> 3, slice = item & 7;
        const int base = tile * 128 + w * 32;
        const char* eimg = eimg0 + (size_t)slice * 262144;   // 512 cols per slice
        bf16x8 a[2][8];
        int frow[2][4];
        float thr[2][4];
#pragma unroll
        for (int m = 0; m < 2; ++m) {
            const int ia = base + m * 16 + l4;
            const int rowa = flag[ia < nflag ? ia : (nflag - 1)];
            const char* rp = ximg + (size_t)rowa * 512;
#pragma unroll
            for (int ts = 0; ts < 8; ++ts) {
                const int byte = ((kg * 16 + ts * 64) + ((rowa & 15) << 5)) & 511;
                a[m][ts] = *(const bf16x8*)(rp + byte);
            }
#pragma unroll
            for (int r = 0; r < 4; ++r) {
                const int ie = base + m * 16 + kg * 4 + r;
                const bool val = ie < nflag;
                const int rowe = flag[val ? ie : (nflag - 1)];
                frow[m][r] = rowe;
                thr[m][r] = val ? ws[WS_ROWTHR + rowe] : -FLT_MAX;
            }
        }
#pragma unroll
        for (int rr = 0; rr < 4; ++rr) {
            const int off = rr * 4096 + w * 1024;
            GLOAD_LDS16(eimg + off + lane * 16, smem + off);
        }
        __syncthreads();

        for (int ch = 0; ch < 16; ++ch) {
            const char* cur = smem + (ch & 1) * 16384;
            if (ch + 1 < 16) {
                const char* src = eimg + (size_t)(ch + 1) * 16384;
                char* nb = smem + ((ch + 1) & 1) * 16384;
#pragma unroll
                for (int rr = 0; rr < 4; ++rr) {
                    const int off = rr * 4096 + w * 1024;
                    GLOAD_LDS16(src + off + lane * 16, nb + off);
                }
            }
            f32x4 acc[2][2];
#pragma unroll
            for (int m = 0; m < 2; ++m)
#pragma unroll
                for (int n = 0; n < 2; ++n) acc[m][n] = 0.f;
#pragma unroll
            for (int ts = 0; ts < 8; ++ts) {
                const int rot = ((kg * 16 + ts * 64) + (l4 << 5)) & 511;
                bf16x8 bfr[2];
#pragma unroll
                for (int n = 0; n < 2; ++n)
                    bfr[n] = *(const bf16x8*)(cur + (n * 16 + l4) * 512 + rot);
#pragma unroll
                for (int m = 0; m < 2; ++m)
#pragma unroll
                    for (int n = 0; n < 2; ++n)
                        acc[m][n] = __builtin_amdgcn_mfma_f32_16x16x32_bf16(a[m][ts], bfr[n], acc[m][n], 0, 0, 0);
            }
#pragma unroll
            for (int n = 0; n < 2; ++n) {
                const int col = slice * 512 + ch * 32 + n * 16 + l4;
                const float bc = bvec[col];
#pragma unroll
                for (int m = 0; m < 2; ++m)
#pragma unroll
                    for (int r = 0; r < 4; ++r) {
                        const float s = fmaf(-2.f, acc[m][n][r], bc);
                        if (s <= thr[m][r]) {
                            const int rr2 = frow[m][r];
                            const int pos = atomicAdd(&cnt[rr2], 1);
                            if (pos < CAP) cand[(size_t)rr2 * CAP + pos] = col;
                        }
                    }
            }
            __syncthreads();
        }
    }
}

// ===== K7: exact fp32 resolve for flagged rows =====
__global__ __launch_bounds__(256) void k_resolve_f(const float* __restrict__ x,
                                                   float* __restrict__ ws,
                                                   float* __restrict__ out) {
    const int t = threadIdx.x, lane = t & 63;
    const int gw = (blockIdx.x * 256 + t) >> 6;     // 1024 waves
    const int nflag = *(const int*)(ws + WS_NFLAG);
    const int* flag = (const int*)(ws + WS_FLAG);
    const int* cnt = (const int*)(ws + WS_CNT);
    const int* cand = (const int*)(ws + WS_CAND);
    const float* eprow = ws + WS_EPROW;
    const float* bvec = ws + WS_BVEC;
    int* idx_int = (int*)(ws + WS_IDX);
    for (int i = gw; i < nflag; i += 1024) {
        const int row = flag[i];
        const float4 xr = ((const float4*)(x + (size_t)row * DDIM))[lane];
        const int n = cnt[row];
        float bestv = FLT_MAX;
        int bestk = KDIM;
        if (n >= 1 && n <= CAP) {
            for (int c = 0; c < n; ++c) {
                const int k = cand[(size_t)row * CAP + c];
                const float4 er = ((const float4*)(eprow + (size_t)k * DDIM))[lane];
                float p = xr.x * er.x + xr.y * er.y + xr.z * er.z + xr.w * er.w;
                p += __shfl_xor(p, 32); p += __shfl_xor(p, 16); p += __shfl_xor(p, 8);
                p += __shfl_xor(p, 4);  p += __shfl_xor(p, 2);  p += __shfl_xor(p, 1);
                const float s = fmaf(-2.f, p, bvec[k]);
                if (s < bestv || (s == bestv && k < bestk)) { bestv = s; bestk = k; }
            }
        } else {   // overflow / safety fallback: exact full scan
            for (int k = 0; k < KDIM; ++k) {
                const float4 er = ((const float4*)(eprow + (size_t)k * DDIM))[lane];
                float p = xr.x * er.x + xr.y * er.y + xr.z * er.z + xr.w * er.w;
                p += __shfl_xor(p, 32); p += __shfl_xor(p, 16); p += __shfl_xor(p, 8);
                p += __shfl_xor(p, 4);  p += __shfl_xor(p, 2);  p += __shfl_xor(p, 1);
                const float s = fmaf(-2.f, p, bvec[k]);
                if (s < bestv || (s == bestv && k < bestk)) { bestv = s; bestk = k; }
            }
        }
        if (lane == 0) { out[O_IDX + row] = (float)bestk; idx_int[row] = bestk; }
    }
}

// ===== K8a: histogram of cluster assignments (int atomics) =====
__global__ __launch_bounds__(256) void k_hist(float* __restrict__ ws) {
    const int r = blockIdx.x * 256 + threadIdx.x;
    const int k = ((const int*)(ws + WS_IDX))[r];
    atomicAdd((int*)(ws + WS_HIST) + k, 1);
}

// ===== K8b: dual exclusive prefix sums: row starts + segment starts =====
__global__ __launch_bounds__(256) void k_scan(float* __restrict__ ws) {
    __shared__ int lsum[256], lseg[256];
    const int t = threadIdx.x;
    const int* hist = (const int*)(ws + WS_HIST);
    int h[16];
    int s = 0, g = 0;
#pragma unroll
    for (int i = 0; i < 16; ++i) {
        h[i] = hist[t * 16 + i];
        s += h[i];
        g += (h[i] + SEG - 1) / SEG;
    }
    lsum[t] = s; lseg[t] = g;
    __syncthreads();
    int v = s, u = g;
    for (int off = 1; off < 256; off <<= 1) {
        const int av = (t >= off) ? lsum[t - off] : 0;
        const int au = (t >= off) ? lseg[t - off] : 0;
        __syncthreads();
        v += av; u += au;
        lsum[t] = v; lseg[t] = u;
        __syncthreads();
    }
    int runs = v - s, rung = u - g;
    int* start = (int*)(ws + WS_START);
    int* fillpos = (int*)(ws + WS_FILLPOS);
    int* segst = (int*)(ws + WS_SEGSTART);
#pragma unroll
    for (int i = 0; i < 16; ++i) {
        start[t * 16 + i] = runs;
        fillpos[t * 16 + i] = runs;
        segst[t * 16 + i] = rung;
        runs += h[i];
        rung += (h[i] + SEG - 1) / SEG;
    }
    if (t == 255) {
        segst[KDIM] = rung;
        *(int*)(ws + WS_NSEG) = rung;
    }
}

// ===== K8c: fill per-cluster row lists =====
__global__ __launch_bounds__(256) void k_fill(float* __restrict__ ws) {
    const int r = blockIdx.x * 256 + threadIdx.x;
    const int k = ((const int*)(ws + WS_IDX))[r];
    const int pos = atomicAdd((int*)(ws + WS_FILLPOS) + k, 1);
    ((int*)(ws + WS_ROWLIST))[pos] = r;
}

// ===== K8d: write segment descriptors (deterministic) =====
__global__ __launch_bounds__(256) void k_segfill(float* __restrict__ ws) {
    const int k = blockIdx.x * 256 + threadIdx.x;
    const int* segst = (const int*)(ws + WS_SEGSTART);
    const int base = segst[k];
    const int ns = segst[k + 1] - base;
    int* seglist = (int*)(ws + WS_SEGLIST);
    for (int j = 0; j < ns; ++j) seglist[base + j] = (k << 10) | j;
}

// ===== K8e: per-segment gather partial sums (<=128 rows each) =====
__global__ __launch_bounds__(256) void k_gather_seg(const float* __restrict__ x,
                                                    float* __restrict__ ws) {
    const int b = blockIdx.x;
    if (b >= *(const int*)(ws + WS_NSEG)) return;
    const int e = ((const int*)(ws + WS_SEGLIST))[b];
    const int k = e >> 10, j = e & 1023;
    const int base = ((const int*)(ws + WS_START))[k];
    const int n = ((const int*)(ws + WS_HIST))[k];
    const int st = base + j * SEG;
    const int en = min(st + SEG, base + n);
    const int* rowlist = (const int*)(ws + WS_ROWLIST);
    const int d = threadIdx.x;
    float s0 = 0.f, s1 = 0.f, s2 = 0.f, s3 = 0.f;
    int i = st;
    for (; i + 3 < en; i += 4) {
        s0 += x[(size_t)rowlist[i]     * DDIM + d];
        s1 += x[(size_t)rowlist[i + 1] * DDIM + d];
        s2 += x[(size_t)rowlist[i + 2] * DDIM + d];
        s3 += x[(size_t)rowlist[i + 3] * DDIM + d];
    }
    for (; i < en; ++i) s0 += x[(size_t)rowlist[i] * DDIM + d];
    (ws + WS_DWPART)[(size_t)b * DDIM + d] = (s0 + s1) + (s2 + s3);
}

// ===== K9a: EMA cluster size + n_total =====
__global__ __launch_bounds__(256) void k_ema_cs(const float* __restrict__ cs_in,
                                                float* __restrict__ ws) {
    __shared__ float red[256];
    const int t = threadIdx.x;
    const int* hist = (const int*)(ws + WS_HIST);
    float part = 0.f;
    for (int k = t; k < KDIM; k += 256) {
        const float ncs = cs_in[k] * DECAYV + (1.0f - DECAYV) * (float)hist[k];
        ws[WS_NCSRAW + k] = ncs;
        part += ncs;
    }
    red[t] = part;
    __syncthreads();
    for (int s = 128; s > 0; s >>= 1) { if (t < s) red[t] += red[t + s]; __syncthreads(); }
    if (t == 0) ws[WS_NTOT] = red[0];
}

// ===== K9b: streaming finalize [K,D] outputs (sums <=ns partials) =====
__global__ __launch_bounds__(256) void k_final(const float* __restrict__ ema_w,
                                               const float* __restrict__ ws,
                                               float* __restrict__ out) {
    const int k = blockIdx.x;   // 4096 blocks
    const int d = threadIdx.x;
    const int* segst = (const int*)(ws + WS_SEGSTART);
    const int ss = segst[k];
    const int ns = segst[k + 1] - ss;
    const float* dwpart = ws + WS_DWPART;
    float a0 = 0.f, a1 = 0.f;
    int j = 0;
    for (; j + 1 < ns; j += 2) {
        a0 += dwpart[(size_t)(ss + j)     * DDIM + d];
        a1 += dwpart[(size_t)(ss + j + 1) * DDIM + d];
    }
    if (j < ns) a0 += dwpart[(size_t)(ss + j) * DDIM + d];
    const float dwsum = a0 + a1;
    const int n = ((const int*)(ws + WS_HIST))[k];
    const float ntot = ws[WS_NTOT];
    const float ncs  = (ws[WS_NCSRAW + k] + 1e-5f) / (ntot + (float)KDIM * 1e-5f) * ntot;
    const float mn   = ws[WS_MEAN + d];
    const float rs   = ws[WS_RSTD + d];
    const size_t e   = (size_t)k * DDIM + d;
    const float dw   = (dwsum - (float)n * mn) * rs;
    const float nw   = ema_w[e] * DECAYV + (1.0f - DECAYV) * dw;
    const float nemb = nw / ncs;
    const float eo   = nemb * sqrtf(ws[WS_NRVAR + d] + EPSV) + ws[WS_NRMEAN + d];
    out[O_EMB + e]  = nemb;
    out[O_EOUT + e] = eo;
    out[O_EMAW + e] = nw;
    if (d == 0) out[O_CS + k] = ncs;
}

// ===== launcher =====
extern "C" void kernel_launch(void* const* d_in, const int* in_sizes, int n_in,
                              void* d_out, int out_size, void* d_ws, size_t ws_size,
                              hipStream_t stream) {
    const float* x     = (const float*)d_in[0];
    const float* emb   = (const float*)d_in[1];
    const float* cs    = (const float*)d_in[2];
    const float* ema_w = (const float*)d_in[3];
    const float* rmean = (const float*)d_in[4];
    const float* rvar  = (const float*)d_in[5];
    float* out = (float*)d_out;
    float* ws  = (float*)d_ws;

    // zero cnt + nflag + hist (contiguous at ws base, ~280 KB)
    hipMemsetAsync(ws, 0, WS_ZEND * sizeof(float), stream);

    k_bnpack<<<2048, 128, 0, stream>>>(x, ws);
    k_bn_mid<<<256, 256, 0, stream>>>(ws);
    k_bn_final<<<1, 256, 0, stream>>>(rmean, rvar, ws, out);
    k_eprime<<<KDIM, 128, 0, stream>>>(emb, ws);

    constexpr int LDSB = 32768;
    k_gemm_min<<<2048, 256, LDSB, stream>>>(ws);
    k_flag<<<NROWS / 256, 256, 0, stream>>>(ws, out);
    k_cand<<<512, 256, LDSB, stream>>>(ws);
    k_resolve_f<<<256, 256, 0, stream>>>(x, ws, out);

    k_hist<<<NROWS / 256, 256, 0, stream>>>(ws);
    k_scan<<<1, 256, 0, stream>>>(ws);
    k_fill<<<NROWS / 256, 256, 0, stream>>>(ws);
    k_segfill<<<KDIM / 256, 256, 0, stream>>>(ws);
    k_gather_seg<<<4608, 256, 0, stream>>>(x, ws);
    k_ema_cs<<<1, 256, 0, stream>>>(cs, ws);
    k_final<<<KDIM, 256, 0, stream>>>(ema_w, ws, out);
}